// Round 10
// baseline (204.424 us; speedup 1.0000x reference)
//
#include <hip/hip_runtime.h>
#include <stdint.h>
#include <math.h>

#define EMBED 1024
#define HEADS 16
#define HDIM  64
#define SEQ   2048
#define BATCH 2

typedef __bf16 bf16x8 __attribute__((ext_vector_type(8)));
typedef float  f32x4  __attribute__((ext_vector_type(4)));
typedef unsigned short u16x8 __attribute__((ext_vector_type(8)));
typedef unsigned short u16x4 __attribute__((ext_vector_type(4)));
typedef uint32_t u32x4v __attribute__((ext_vector_type(4)));

static __device__ __forceinline__ unsigned short f2bf(float f){
  union { float f; uint32_t u; } v; v.f = f;
  uint32_t u = v.u;
  uint32_t r = (u + 0x7FFFu + ((u >> 16) & 1u)) >> 16;  // RNE
  return (unsigned short)r;
}
static __device__ __forceinline__ bf16x8 as_bf(u16x8 v){ return __builtin_bit_cast(bf16x8, v); }

static __device__ __forceinline__ uint32_t pk_bf16(float a, float b){
#if defined(__has_builtin) && __has_builtin(__builtin_amdgcn_cvt_pk_bf16_f32)
  typedef __bf16 bf16x2 __attribute__((ext_vector_type(2)));
  bf16x2 p = __builtin_amdgcn_cvt_pk_bf16_f32(a, b);
  return __builtin_bit_cast(uint32_t, p);
#else
  return (uint32_t)f2bf(a) | ((uint32_t)f2bf(b) << 16);
#endif
}

static __device__ __forceinline__ float fexp2(float x){
#if defined(__has_builtin) && __has_builtin(__builtin_amdgcn_exp2f)
  return __builtin_amdgcn_exp2f(x);
#else
  return exp2f(x);
#endif
}

// async global->LDS, 16B per lane. lp_wave must be WAVE-UNIFORM; HW adds lane*16.
static __device__ __forceinline__ void stage16(const unsigned short* gp,
                                               unsigned short* lp_wave, int lane){
#if defined(__has_builtin) && __has_builtin(__builtin_amdgcn_global_load_lds)
  __builtin_amdgcn_global_load_lds((const __attribute__((address_space(1))) void*)gp,
                                   (__attribute__((address_space(3))) void*)lp_wave,
                                   16, 0, 0);
#else
  *(u16x8*)(lp_wave + lane * 8) = *(const u16x8*)gp;
#endif
}

// ---------------- prep: cast x -> bf16, W_qkv -> wqkvT bf16 -------------------------
__global__ __launch_bounds__(256) void prep(
    const float* __restrict__ x,      unsigned short* __restrict__ xb,
    const float* __restrict__ W_qkv,  unsigned short* __restrict__ wqkvT)
{
  __shared__ unsigned short T[32 * 36];
  const int bid = blockIdx.x;
  const int t   = threadIdx.x;

  if (bid < 4096){
    int i = (bid * 256 + t) * 4;
    float4 v = *(const float4*)(x + i);
    u16x4 o;
    o[0] = f2bf(v.x); o[1] = f2bf(v.y); o[2] = f2bf(v.z); o[3] = f2bf(v.w);
    *(u16x4*)(xb + i) = o;
    return;
  }
  int idx = bid - 4096;
  int n0 = (idx % 96) * 32, k0 = (idx / 96) * 32;
  int kr = t >> 3, nc = (t & 7) * 4;
  float4 wv = *(const float4*)(W_qkv + (size_t)(k0 + kr) * 3072 + n0 + nc);
  T[(nc + 0) * 36 + kr] = f2bf(wv.x);
  T[(nc + 1) * 36 + kr] = f2bf(wv.y);
  T[(nc + 2) * 36 + kr] = f2bf(wv.z);
  T[(nc + 3) * 36 + kr] = f2bf(wv.w);
  __syncthreads();
  int nr = t >> 3, kc = (t & 7) * 4;
  *(u16x4*)(wqkvT + (size_t)(n0 + nr) * 1024 + k0 + kc) = *(const u16x4*)&T[nr * 36 + kc];
}

// ---------------- W_out[K][N] fp32 -> woutT[N][K] bf16 ------------------------------
__global__ __launch_bounds__(256) void wtrans_out(const float* __restrict__ W,
                                                  unsigned short* __restrict__ Wt){
  __shared__ unsigned short T[32 * 36];
  int t = threadIdx.x;
  int n0 = blockIdx.x * 32, k0 = blockIdx.y * 32;
  int kr = t >> 3, nc = (t & 7) * 4;
  float4 wv = *(const float4*)(W + (size_t)(k0 + kr) * 1024 + n0 + nc);
  T[(nc + 0) * 36 + kr] = f2bf(wv.x);
  T[(nc + 1) * 36 + kr] = f2bf(wv.y);
  T[(nc + 2) * 36 + kr] = f2bf(wv.z);
  T[(nc + 3) * 36 + kr] = f2bf(wv.w);
  __syncthreads();
  int nr = t >> 3, kc = (t & 7) * 4;
  *(u16x4*)(Wt + (size_t)(n0 + nr) * 1024 + k0 + kc) = *(const u16x4*)&T[nr * 36 + kc];
}

// ---------------- V[bh][S][Hd] -> VT[bh][Hd][S], PV-permuted cols -------------------
// pos(kv) = g*8 + hi*4 + r where kv = 16*hi + 4*g + r (S^T C-layout A-frag order).
__global__ __launch_bounds__(256) void vtrans(const unsigned short* __restrict__ V,
                                              unsigned short* __restrict__ VT){
  __shared__ unsigned short T[32 * 36];
  int t = threadIdx.x;
  int s0 = blockIdx.x * 32, d0 = blockIdx.y * 32;
  size_t base = (size_t)blockIdx.z * SEQ * HDIM;
  int sr = t >> 3, dc = (t & 7) * 4;
  u16x4 vv = *(const u16x4*)(V + base + (size_t)(s0 + sr) * HDIM + d0 + dc);
  T[(dc + 0) * 36 + sr] = vv[0];
  T[(dc + 1) * 36 + sr] = vv[1];
  T[(dc + 2) * 36 + sr] = vv[2];
  T[(dc + 3) * 36 + sr] = vv[3];
  __syncthreads();
  int dr = t >> 3, sc = (t & 7) * 4;
  int pos = (((sc >> 2) & 3) << 3) + (((sc >> 4) & 1) << 2); // g*8 + hi*4
  *(u16x4*)(VT + base + (size_t)(d0 + dr) * SEQ + s0 + pos) = *(const u16x4*)&T[dr * 36 + sc];
}

// ---------------- QKV GEMM (BK=64) --------------------------------------------------
__global__ __launch_bounds__(256) void gemm_qkv(
    const unsigned short* __restrict__ A,
    const unsigned short* __restrict__ Bt,
    const float* __restrict__ bias,
    unsigned short* __restrict__ q_ws,
    unsigned short* __restrict__ k_ws,
    unsigned short* __restrict__ v_ws,
    int M, int N, int K)
{
  __shared__ unsigned short As[128 * 64];   // 16KB
  __shared__ unsigned short Bs[128 * 64];   // 16KB
  const int tid  = threadIdx.x;
  const int bm   = blockIdx.y, bn = blockIdx.x;
  const int w    = tid >> 6, lane = tid & 63;
  const int quad = lane >> 4, l16 = lane & 15;
  const int wm   = (w >> 1) * 64, wn = (w & 1) * 64;

  f32x4 acc[4][4] = {};

  for (int k0 = 0; k0 < K; k0 += 64) {
    #pragma unroll
    for (int i = 0; i < 4; i++){
      int c = w + i * 4;                 // 16 chunks of 8 rows x 1KB
      int row = c * 8 + (lane >> 3);
      int kg = (lane & 7) ^ (row & 7);
      stage16(A  + (size_t)(bm * 128 + row) * K + k0 + kg * 8, &As[c * 512], lane);
      stage16(Bt + (size_t)(bn * 128 + row) * K + k0 + kg * 8, &Bs[c * 512], lane);
    }
    __syncthreads();

    #pragma unroll
    for (int ks = 0; ks < 2; ks++){
      bf16x8 af[4], bfr[4];
      #pragma unroll
      for (int t = 0; t < 4; t++){
        int ra = wm + t * 16 + l16;
        int rb = wn + t * 16 + l16;
        af[t]  = as_bf(*(const u16x8*)&As[(ra << 6) + ((((ks << 2) + quad) ^ (ra & 7)) << 3)]);
        bfr[t] = as_bf(*(const u16x8*)&Bs[(rb << 6) + ((((ks << 2) + quad) ^ (rb & 7)) << 3)]);
      }
      #pragma unroll
      for (int mt = 0; mt < 4; mt++)
        #pragma unroll
        for (int nt = 0; nt < 4; nt++)
          acc[mt][nt] = __builtin_amdgcn_mfma_f32_16x16x32_bf16(af[mt], bfr[nt], acc[mt][nt], 0, 0, 0);
    }
    __syncthreads();
  }

  const int which = (bn * 128) >> 10;   // block-uniform: 0=Q 1=K 2=V
  unsigned short* dst = (which == 0) ? q_ws : (which == 1) ? k_ws : v_ws;
  const float scale = (which == 0) ? 0.18033688f : 1.0f;  // Q: 1/sqrt(Hd)*log2(e)
  const int b = bm >> 4;
  #pragma unroll
  for (int nt = 0; nt < 4; nt++){
    int gnb = bn * 128 + wn + nt * 16;
    int h   = (gnb & 1023) >> 6;
    int hd  = (gnb & 63) + l16;
    float bv = bias[gnb + l16];
    unsigned short* dp = dst + (size_t)(b * HEADS + h) * SEQ * HDIM + hd;
    #pragma unroll
    for (int mt = 0; mt < 4; mt++){
      int s0 = ((bm & 15) * 128) + wm + mt * 16 + quad * 4;
      #pragma unroll
      for (int r = 0; r < 4; r++)
        dp[(size_t)(s0 + r) * HDIM] = f2bf((acc[mt][nt][r] + bv) * scale);
    }
  }
}

// ---------------- out-proj GEMM (BK=64): BM=128, BN=64 ------------------------------
__global__ __launch_bounds__(256) void gemm_out(
    const unsigned short* __restrict__ A,
    const unsigned short* __restrict__ Bt,
    const float* __restrict__ bias,
    float* __restrict__ Cout,
    int M, int N, int K)
{
  __shared__ unsigned short As[128 * 64];   // 16KB
  __shared__ unsigned short Bs[64 * 64];    // 8KB
  const int tid  = threadIdx.x;
  const int bm   = blockIdx.y, bn = blockIdx.x;
  const int w    = tid >> 6, lane = tid & 63;
  const int quad = lane >> 4, l16 = lane & 15;
  const int wm   = (w >> 1) * 64, wn = (w & 1) * 32;

  f32x4 acc[4][2] = {};

  for (int k0 = 0; k0 < K; k0 += 64) {
    #pragma unroll
    for (int i = 0; i < 4; i++){
      int c = w + i * 4;                 // A: 16 chunks of 8 rows
      int row = c * 8 + (lane >> 3);
      int kg = (lane & 7) ^ (row & 7);
      stage16(A + (size_t)(bm * 128 + row) * K + k0 + kg * 8, &As[c * 512], lane);
    }
    #pragma unroll
    for (int i = 0; i < 2; i++){
      int c = w + i * 4;                 // B: 8 chunks of 8 rows
      int row = c * 8 + (lane >> 3);
      int kg = (lane & 7) ^ (row & 7);
      stage16(Bt + (size_t)(bn * 64 + row) * K + k0 + kg * 8, &Bs[c * 512], lane);
    }
    __syncthreads();

    #pragma unroll
    for (int ks = 0; ks < 2; ks++){
      bf16x8 af[4], bfr[2];
      #pragma unroll
      for (int t = 0; t < 4; t++){
        int ra = wm + t * 16 + l16;
        af[t] = as_bf(*(const u16x8*)&As[(ra << 6) + ((((ks << 2) + quad) ^ (ra & 7)) << 3)]);
      }
      #pragma unroll
      for (int t = 0; t < 2; t++){
        int rb = wn + t * 16 + l16;
        bfr[t] = as_bf(*(const u16x8*)&Bs[(rb << 6) + ((((ks << 2) + quad) ^ (rb & 7)) << 3)]);
      }
      #pragma unroll
      for (int mt = 0; mt < 4; mt++)
        #pragma unroll
        for (int nt = 0; nt < 2; nt++)
          acc[mt][nt] = __builtin_amdgcn_mfma_f32_16x16x32_bf16(af[mt], bfr[nt], acc[mt][nt], 0, 0, 0);
    }
    __syncthreads();
  }

  #pragma unroll
  for (int mt = 0; mt < 4; mt++)
    #pragma unroll
    for (int nt = 0; nt < 2; nt++)
      #pragma unroll
      for (int r = 0; r < 4; r++){
        int gm = bm * 128 + wm + mt * 16 + quad * 4 + r;
        int gn = bn * 64 + wn + nt * 16 + l16;
        Cout[(size_t)gm * N + gn] = acc[mt][nt][r] + bias[gn];
      }
}

// ---------------- flash attention (S^T trick, 8 waves, single-barrier dbuf,
//                   kt-loop unrolled x2 so LDS addresses are loop-invariant) --------
__global__ __launch_bounds__(512) void attn(
    const unsigned short* __restrict__ q_ws,
    const unsigned short* __restrict__ k_ws,
    const unsigned short* __restrict__ vt_ws,
    unsigned short* __restrict__ o_ws)
{
  __shared__ unsigned short Qs[128 * 64];     // 16KB
  __shared__ unsigned short Ks[2][64 * 64];   // 16KB
  __shared__ unsigned short VTs[2][64 * 64];  // 16KB  [d][kv-pos]
  const int tid  = threadIdx.x;
  const int qt   = blockIdx.x, bh = blockIdx.y;
  const int w    = tid >> 6, lane = tid & 63;
  const int quad = lane >> 4, l16 = lane & 15;
  const size_t base = (size_t)bh * SEQ * HDIM;

  #pragma unroll
  for (int i = 0; i < 2; i++){
    int c = w * 2 + i;
    int row = c * 8 + (lane >> 3);
    int kg = (lane & 7) ^ (row & 7);
    stage16(q_ws + base + (size_t)(qt * 128 + row) * HDIM + kg * 8, &Qs[c * 512], lane);
  }

  const int srow = w * 8 + (lane >> 3);
  const int skg  = (lane & 7) ^ (srow & 7);
  const int dofs = w * 512 + lane * 8;

  stage16(k_ws  + base + (size_t)srow * HDIM + skg * 8, &Ks[0][w * 512],  lane);
  stage16(vt_ws + base + (size_t)srow * SEQ + skg * 8,  &VTs[0][w * 512], lane);
  __syncthreads();

  bf16x8 bq[2];
  {
    int row = w * 16 + l16;
    #pragma unroll
    for (int ks = 0; ks < 2; ks++)
      bq[ks] = as_bf(*(const u16x8*)&Qs[(row << 6) + ((((ks << 2) + quad) ^ (row & 7)) << 3)]);
  }

  const unsigned short* kp = k_ws  + base + (size_t)(64 + srow) * HDIM + skg * 8;
  const unsigned short* vp = vt_ws + base + (size_t)srow * SEQ + 64 + skg * 8;

  f32x4 acc[4] = {};
  float li = 0.f;

  for (int kt2 = 0; kt2 < SEQ / 128; kt2++){
    #pragma unroll
    for (int half = 0; half < 2; half++){
      const int cur = half;               // compile-time after unroll
      const int kt  = kt2 * 2 + half;
      u16x8 kpre, vpre;
      if (kt < SEQ / 64 - 1){
        kpre = *(const u16x8*)kp;  kp += 64 * HDIM;
        vpre = *(const u16x8*)vp;  vp += 64;
      }

      f32x4 sf[4] = {};
      #pragma unroll
      for (int ks = 0; ks < 2; ks++){
        #pragma unroll
        for (int nt = 0; nt < 4; nt++){
          int rk = nt * 16 + l16;
          bf16x8 ak = as_bf(*(const u16x8*)&Ks[cur][(rk << 6) + ((((ks << 2) + quad) ^ (rk & 7)) << 3)]);
          sf[nt] = __builtin_amdgcn_mfma_f32_16x16x32_bf16(ak, bq[ks], sf[nt], 0, 0, 0);
        }
      }

      #pragma unroll
      for (int nt = 0; nt < 4; nt++)
        #pragma unroll
        for (int r = 0; r < 4; r++)
          sf[nt][r] = fexp2(sf[nt][r]);
      #pragma unroll
      for (int nt = 0; nt < 4; nt++)
        li += (sf[nt][0] + sf[nt][1]) + (sf[nt][2] + sf[nt][3]);

      #pragma unroll
      for (int c = 0; c < 2; c++){
        u32x4v aw;
        aw[0] = pk_bf16(sf[c * 2][0],     sf[c * 2][1]);
        aw[1] = pk_bf16(sf[c * 2][2],     sf[c * 2][3]);
        aw[2] = pk_bf16(sf[c * 2 + 1][0], sf[c * 2 + 1][1]);
        aw[3] = pk_bf16(sf[c * 2 + 1][2], sf[c * 2 + 1][3]);
        bf16x8 ap = __builtin_bit_cast(bf16x8, aw);
        #pragma unroll
        for (int nt = 0; nt < 4; nt++){
          int rv = nt * 16 + l16;
          bf16x8 bv = as_bf(*(const u16x8*)&VTs[cur][(rv << 6) + ((((c << 2) + quad) ^ (rv & 7)) << 3)]);
          acc[nt] = __builtin_amdgcn_mfma_f32_16x16x32_bf16(ap, bv, acc[nt], 0, 0, 0);
        }
      }

      if (kt < SEQ / 64 - 1){
        *(u16x8*)&Ks[cur ^ 1][dofs]  = kpre;
        *(u16x8*)&VTs[cur ^ 1][dofs] = vpre;
      }
      __syncthreads();
    }
  }

  li += __shfl_xor(li, 16);
  li += __shfl_xor(li, 32);
  float inv = 1.0f / li;
  float invr[4];
  #pragma unroll
  for (int r = 0; r < 4; r++)
    invr[r] = __shfl(inv, quad * 4 + r);

  int b = bh >> 4, h = bh & 15;
  #pragma unroll
  for (int nt = 0; nt < 4; nt++)
    #pragma unroll
    for (int r = 0; r < 4; r++){
      int s = qt * 128 + w * 16 + quad * 4 + r;
      int d = h * 64 + nt * 16 + l16;
      o_ws[((size_t)(b * SEQ + s)) * EMBED + d] = f2bf(acc[nt][r] * invr[r]);
    }
}

// ---------------- launch ----------------
// ws alias table (40 MB), R9-proven ordering:
//   [0,8M)   xb -> o     [8,16M) q     [16,24M) k
//   [24,32M) v (dead after vtrans) -> woutT [24,26M) via wtrans_out AFTER vtrans
//   [32,38M) wqkvT (dead after gemm_qkv) -> vt [32,40M)
extern "C" void kernel_launch(void* const* d_in, const int* in_sizes, int n_in,
                              void* d_out, int out_size, void* d_ws, size_t ws_size,
                              hipStream_t stream) {
  const float* x     = (const float*)d_in[0];
  const float* W_qkv = (const float*)d_in[1];
  const float* b_qkv = (const float*)d_in[2];
  const float* W_out = (const float*)d_in[3];
  const float* b_out = (const float*)d_in[4];
  float* out = (float*)d_out;

  char* ws = (char*)d_ws;
  unsigned short* xb    = (unsigned short*)(ws);
  unsigned short* q     = (unsigned short*)(ws + ((size_t)8  << 20));
  unsigned short* k     = (unsigned short*)(ws + ((size_t)16 << 20));
  unsigned short* v     = (unsigned short*)(ws + ((size_t)24 << 20));
  unsigned short* woutT = (unsigned short*)(ws + ((size_t)24 << 20));
  unsigned short* vt    = (unsigned short*)(ws + ((size_t)32 << 20));
  unsigned short* wqkvT = (unsigned short*)(ws + ((size_t)32 << 20));
  unsigned short* o     = xb;

  prep<<<dim3(7168), dim3(256), 0, stream>>>(x, xb, W_qkv, wqkvT);

  gemm_qkv<<<dim3(24, 32), dim3(256), 0, stream>>>(
      xb, wqkvT, b_qkv, q, k, v, 4096, 3072, 1024);

  vtrans<<<dim3(64, 2, 32), dim3(256), 0, stream>>>(v, vt);

  wtrans_out<<<dim3(32, 32), dim3(256), 0, stream>>>(W_out, woutT);

  attn<<<dim3(16, 32), dim3(512), 0, stream>>>(q, k, vt, o);

  gemm_out<<<dim3(16, 32), dim3(256), 0, stream>>>(
      o, woutT, b_out, out, 4096, 1024, 1024);
}

// Round 11
// 197.791 us; speedup vs baseline: 1.0335x; 1.0335x over previous
//
#include <hip/hip_runtime.h>
#include <stdint.h>
#include <math.h>

#define EMBED 1024
#define HEADS 16
#define HDIM  64
#define SEQ   2048
#define BATCH 2

typedef __bf16 bf16x8 __attribute__((ext_vector_type(8)));
typedef float  f32x4  __attribute__((ext_vector_type(4)));
typedef unsigned short u16x8 __attribute__((ext_vector_type(8)));
typedef unsigned short u16x4 __attribute__((ext_vector_type(4)));
typedef uint32_t u32x4v __attribute__((ext_vector_type(4)));

static __device__ __forceinline__ unsigned short f2bf(float f){
  union { float f; uint32_t u; } v; v.f = f;
  uint32_t u = v.u;
  uint32_t r = (u + 0x7FFFu + ((u >> 16) & 1u)) >> 16;  // RNE
  return (unsigned short)r;
}
static __device__ __forceinline__ bf16x8 as_bf(u16x8 v){ return __builtin_bit_cast(bf16x8, v); }

static __device__ __forceinline__ uint32_t pk_bf16(float a, float b){
#if defined(__has_builtin) && __has_builtin(__builtin_amdgcn_cvt_pk_bf16_f32)
  typedef __bf16 bf16x2 __attribute__((ext_vector_type(2)));
  bf16x2 p = __builtin_amdgcn_cvt_pk_bf16_f32(a, b);
  return __builtin_bit_cast(uint32_t, p);
#else
  return (uint32_t)f2bf(a) | ((uint32_t)f2bf(b) << 16);
#endif
}

static __device__ __forceinline__ float fexp2(float x){
#if defined(__has_builtin) && __has_builtin(__builtin_amdgcn_exp2f)
  return __builtin_amdgcn_exp2f(x);
#else
  return exp2f(x);
#endif
}

// async global->LDS, 16B per lane. lp_wave must be WAVE-UNIFORM; HW adds lane*16.
static __device__ __forceinline__ void stage16(const unsigned short* gp,
                                               unsigned short* lp_wave, int lane){
#if defined(__has_builtin) && __has_builtin(__builtin_amdgcn_global_load_lds)
  __builtin_amdgcn_global_load_lds((const __attribute__((address_space(1))) void*)gp,
                                   (__attribute__((address_space(3))) void*)lp_wave,
                                   16, 0, 0);
#else
  *(u16x8*)(lp_wave + lane * 8) = *(const u16x8*)gp;
#endif
}

// ---------------- prep: cast x -> bf16, W_qkv -> wqkvT bf16 -------------------------
__global__ __launch_bounds__(256) void prep(
    const float* __restrict__ x,      unsigned short* __restrict__ xb,
    const float* __restrict__ W_qkv,  unsigned short* __restrict__ wqkvT)
{
  __shared__ unsigned short T[32 * 36];
  const int bid = blockIdx.x;
  const int t   = threadIdx.x;

  if (bid < 4096){
    int i = (bid * 256 + t) * 4;
    float4 v = *(const float4*)(x + i);
    u16x4 o;
    o[0] = f2bf(v.x); o[1] = f2bf(v.y); o[2] = f2bf(v.z); o[3] = f2bf(v.w);
    *(u16x4*)(xb + i) = o;
    return;
  }
  int idx = bid - 4096;
  int n0 = (idx % 96) * 32, k0 = (idx / 96) * 32;
  int kr = t >> 3, nc = (t & 7) * 4;
  float4 wv = *(const float4*)(W_qkv + (size_t)(k0 + kr) * 3072 + n0 + nc);
  T[(nc + 0) * 36 + kr] = f2bf(wv.x);
  T[(nc + 1) * 36 + kr] = f2bf(wv.y);
  T[(nc + 2) * 36 + kr] = f2bf(wv.z);
  T[(nc + 3) * 36 + kr] = f2bf(wv.w);
  __syncthreads();
  int nr = t >> 3, kc = (t & 7) * 4;
  *(u16x4*)(wqkvT + (size_t)(n0 + nr) * 1024 + k0 + kc) = *(const u16x4*)&T[nr * 36 + kc];
}

// ---------------- W_out[K][N] fp32 -> woutT[N][K] bf16 ------------------------------
__global__ __launch_bounds__(256) void wtrans_out(const float* __restrict__ W,
                                                  unsigned short* __restrict__ Wt){
  __shared__ unsigned short T[32 * 36];
  int t = threadIdx.x;
  int n0 = blockIdx.x * 32, k0 = blockIdx.y * 32;
  int kr = t >> 3, nc = (t & 7) * 4;
  float4 wv = *(const float4*)(W + (size_t)(k0 + kr) * 1024 + n0 + nc);
  T[(nc + 0) * 36 + kr] = f2bf(wv.x);
  T[(nc + 1) * 36 + kr] = f2bf(wv.y);
  T[(nc + 2) * 36 + kr] = f2bf(wv.z);
  T[(nc + 3) * 36 + kr] = f2bf(wv.w);
  __syncthreads();
  int nr = t >> 3, kc = (t & 7) * 4;
  *(u16x4*)(Wt + (size_t)(n0 + nr) * 1024 + k0 + kc) = *(const u16x4*)&T[nr * 36 + kc];
}

// ---------------- V[bh][S][Hd] -> VT[bh][Hd][S], PV-permuted cols -------------------
// pos(kv) = g*8 + hi*4 + r where kv = 16*hi + 4*g + r (S^T C-layout A-frag order).
__global__ __launch_bounds__(256) void vtrans(const unsigned short* __restrict__ V,
                                              unsigned short* __restrict__ VT){
  __shared__ unsigned short T[32 * 36];
  int t = threadIdx.x;
  int s0 = blockIdx.x * 32, d0 = blockIdx.y * 32;
  size_t base = (size_t)blockIdx.z * SEQ * HDIM;
  int sr = t >> 3, dc = (t & 7) * 4;
  u16x4 vv = *(const u16x4*)(V + base + (size_t)(s0 + sr) * HDIM + d0 + dc);
  T[(dc + 0) * 36 + sr] = vv[0];
  T[(dc + 1) * 36 + sr] = vv[1];
  T[(dc + 2) * 36 + sr] = vv[2];
  T[(dc + 3) * 36 + sr] = vv[3];
  __syncthreads();
  int dr = t >> 3, sc = (t & 7) * 4;
  int pos = (((sc >> 2) & 3) << 3) + (((sc >> 4) & 1) << 2); // g*8 + hi*4
  *(u16x4*)(VT + base + (size_t)(d0 + dr) * SEQ + s0 + pos) = *(const u16x4*)&T[dr * 36 + sc];
}

// ---------------- QKV GEMM (BK=32, R9-proven) ---------------------------------------
__global__ __launch_bounds__(256) void gemm_qkv(
    const unsigned short* __restrict__ A,
    const unsigned short* __restrict__ Bt,
    const float* __restrict__ bias,
    unsigned short* __restrict__ q_ws,
    unsigned short* __restrict__ k_ws,
    unsigned short* __restrict__ v_ws,
    int M, int N, int K)
{
  __shared__ unsigned short As[128 * 32];
  __shared__ unsigned short Bs[128 * 32];
  const int tid  = threadIdx.x;
  const int bm   = blockIdx.y, bn = blockIdx.x;
  const int w    = tid >> 6, lane = tid & 63;
  const int quad = lane >> 4, l16 = lane & 15;
  const int wm   = (w >> 1) * 64, wn = (w & 1) * 64;

  f32x4 acc[4][4] = {};

  for (int k0 = 0; k0 < K; k0 += 32) {
    #pragma unroll
    for (int i = 0; i < 2; i++){
      int c = w + i * 4;                 // 8 chunks of 16 rows x 1KB
      int row = c * 16 + (lane >> 2);
      int kg = (lane & 3) ^ (row & 3);   // swizzle folded into global addr
      stage16(A  + (size_t)(bm * 128 + row) * K + k0 + kg * 8, &As[c * 512], lane);
      stage16(Bt + (size_t)(bn * 128 + row) * K + k0 + kg * 8, &Bs[c * 512], lane);
    }
    __syncthreads();

    bf16x8 af[4], bfr[4];
    #pragma unroll
    for (int t = 0; t < 4; t++){
      int ra = wm + t * 16 + l16;
      int rb = wn + t * 16 + l16;
      af[t]  = as_bf(*(const u16x8*)&As[(ra << 5) + ((quad ^ (ra & 3)) << 3)]);
      bfr[t] = as_bf(*(const u16x8*)&Bs[(rb << 5) + ((quad ^ (rb & 3)) << 3)]);
    }
    #pragma unroll
    for (int mt = 0; mt < 4; mt++)
      #pragma unroll
      for (int nt = 0; nt < 4; nt++)
        acc[mt][nt] = __builtin_amdgcn_mfma_f32_16x16x32_bf16(af[mt], bfr[nt], acc[mt][nt], 0, 0, 0);
    __syncthreads();
  }

  const int which = (bn * 128) >> 10;   // block-uniform: 0=Q 1=K 2=V
  unsigned short* dst = (which == 0) ? q_ws : (which == 1) ? k_ws : v_ws;
  const float scale = (which == 0) ? 0.18033688f : 1.0f;  // Q: 1/sqrt(Hd)*log2(e)
  const int b = bm >> 4;
  #pragma unroll
  for (int nt = 0; nt < 4; nt++){
    int gnb = bn * 128 + wn + nt * 16;
    int h   = (gnb & 1023) >> 6;
    int hd  = (gnb & 63) + l16;
    float bv = bias[gnb + l16];
    unsigned short* dp = dst + (size_t)(b * HEADS + h) * SEQ * HDIM + hd;
    #pragma unroll
    for (int mt = 0; mt < 4; mt++){
      int s0 = ((bm & 15) * 128) + wm + mt * 16 + quad * 4;
      #pragma unroll
      for (int r = 0; r < 4; r++)
        dp[(size_t)(s0 + r) * HDIM] = f2bf((acc[mt][nt][r] + bv) * scale);
    }
  }
}

// ---------------- out-proj GEMM (BK=32, R9-proven): BM=128, BN=64 -------------------
__global__ __launch_bounds__(256) void gemm_out(
    const unsigned short* __restrict__ A,
    const unsigned short* __restrict__ Bt,
    const float* __restrict__ bias,
    float* __restrict__ Cout,
    int M, int N, int K)
{
  __shared__ unsigned short As[128 * 32];
  __shared__ unsigned short Bs[64 * 32];
  const int tid  = threadIdx.x;
  const int bm   = blockIdx.y, bn = blockIdx.x;
  const int w    = tid >> 6, lane = tid & 63;
  const int quad = lane >> 4, l16 = lane & 15;
  const int wm   = (w >> 1) * 64, wn = (w & 1) * 32;

  f32x4 acc[4][2] = {};

  for (int k0 = 0; k0 < K; k0 += 32) {
    #pragma unroll
    for (int i = 0; i < 2; i++){
      int c = w + i * 4;
      int row = c * 16 + (lane >> 2);
      int kg = (lane & 3) ^ (row & 3);
      stage16(A + (size_t)(bm * 128 + row) * K + k0 + kg * 8, &As[c * 512], lane);
    }
    {
      int c = w;                          // 4 chunks of 16 rows
      int row = c * 16 + (lane >> 2);
      int kg = (lane & 3) ^ (row & 3);
      stage16(Bt + (size_t)(bn * 64 + row) * K + k0 + kg * 8, &Bs[c * 512], lane);
    }
    __syncthreads();

    bf16x8 af[4], bfr[2];
    #pragma unroll
    for (int t = 0; t < 4; t++){
      int ra = wm + t * 16 + l16;
      af[t] = as_bf(*(const u16x8*)&As[(ra << 5) + ((quad ^ (ra & 3)) << 3)]);
    }
    #pragma unroll
    for (int t = 0; t < 2; t++){
      int rb = wn + t * 16 + l16;
      bfr[t] = as_bf(*(const u16x8*)&Bs[(rb << 5) + ((quad ^ (rb & 3)) << 3)]);
    }
    #pragma unroll
    for (int mt = 0; mt < 4; mt++)
      #pragma unroll
      for (int nt = 0; nt < 2; nt++)
        acc[mt][nt] = __builtin_amdgcn_mfma_f32_16x16x32_bf16(af[mt], bfr[nt], acc[mt][nt], 0, 0, 0);
    __syncthreads();
  }

  #pragma unroll
  for (int mt = 0; mt < 4; mt++)
    #pragma unroll
    for (int nt = 0; nt < 2; nt++)
      #pragma unroll
      for (int r = 0; r < 4; r++){
        int gm = bm * 128 + wm + mt * 16 + quad * 4 + r;
        int gn = bn * 64 + wn + nt * 16 + l16;
        Cout[(size_t)gm * N + gn] = acc[mt][nt][r] + bias[gn];
      }
}

// ---------------- flash attention: mq=2 for 2x LDS-read reuse ------------------------
// block = 512 threads (8 waves), q-tile 256 (32 q-rows per wave, mq=2), kv-tile 64.
// Per wave per iter: 16 LDS B-frag reads feed 32 MFMAs (1:2) — halves the LDS traffic
// per FLOP vs mq=1 (which was LDS-BW-bound 2:1). Grid 8x32 = 256 blocks = 1/CU.
// S^T trick + reg-prefetch + single-barrier dbuf + unroll-by-2 carried over.
__global__ __launch_bounds__(512) void attn(
    const unsigned short* __restrict__ q_ws,
    const unsigned short* __restrict__ k_ws,
    const unsigned short* __restrict__ vt_ws,
    unsigned short* __restrict__ o_ws)
{
  __shared__ unsigned short Qs[256 * 64];     // 32KB
  __shared__ unsigned short Ks[2][64 * 64];   // 16KB
  __shared__ unsigned short VTs[2][64 * 64];  // 16KB  [d][kv-pos]
  const int tid  = threadIdx.x;
  const int qt   = blockIdx.x, bh = blockIdx.y;
  const int w    = tid >> 6, lane = tid & 63;
  const int quad = lane >> 4, l16 = lane & 15;
  const size_t base = (size_t)bh * SEQ * HDIM;

  // stage Q (32 chunks of 8 rows), 4 chunks per wave
  #pragma unroll
  for (int i = 0; i < 4; i++){
    int c = w * 4 + i;
    int row = c * 8 + (lane >> 3);
    int kg = (lane & 7) ^ (row & 7);
    stage16(q_ws + base + (size_t)(qt * 256 + row) * HDIM + kg * 8, &Qs[c * 512], lane);
  }

  // staging geometry for K/VT tiles (8 chunks of 8 rows, 1 per wave)
  const int srow = w * 8 + (lane >> 3);
  const int skg  = (lane & 7) ^ (srow & 7);
  const int dofs = w * 512 + lane * 8;

  // prologue: DMA tile 0 into buffer 0
  stage16(k_ws  + base + (size_t)srow * HDIM + skg * 8, &Ks[0][w * 512],  lane);
  stage16(vt_ws + base + (size_t)srow * SEQ + skg * 8,  &VTs[0][w * 512], lane);
  __syncthreads();

  // hoist Q B-frags (loop-invariant): rows w*32 + mq*16 + l16
  bf16x8 bq[2][2];
  #pragma unroll
  for (int mq = 0; mq < 2; mq++){
    int row = w * 32 + mq * 16 + l16;
    #pragma unroll
    for (int ks = 0; ks < 2; ks++)
      bq[mq][ks] = as_bf(*(const u16x8*)&Qs[(row << 6) + ((((ks << 2) + quad) ^ (row & 7)) << 3)]);
  }

  const unsigned short* kp = k_ws  + base + (size_t)(64 + srow) * HDIM + skg * 8;
  const unsigned short* vp = vt_ws + base + (size_t)srow * SEQ + 64 + skg * 8;

  f32x4 acc[2][4] = {};
  float li[2] = {0.f, 0.f};   // per-lane partial sum for q = w*32 + mq*16 + l16

  for (int kt2 = 0; kt2 < SEQ / 128; kt2++){
    #pragma unroll
    for (int half = 0; half < 2; half++){
      const int cur = half;               // compile-time after unroll
      const int kt  = kt2 * 2 + half;
      u16x8 kpre, vpre;
      if (kt < SEQ / 64 - 1){
        kpre = *(const u16x8*)kp;  kp += 64 * HDIM;
        vpre = *(const u16x8*)vp;  vp += 64;
      }

      // S^T = K Q^T: sf[nt][mq] holds kv rows nt*16+quad*4+r, q col l16
      f32x4 sf[4][2] = {};
      #pragma unroll
      for (int ks = 0; ks < 2; ks++){
        #pragma unroll
        for (int nt = 0; nt < 4; nt++){
          int rk = nt * 16 + l16;
          bf16x8 ak = as_bf(*(const u16x8*)&Ks[cur][(rk << 6) + ((((ks << 2) + quad) ^ (rk & 7)) << 3)]);
          #pragma unroll
          for (int mq = 0; mq < 2; mq++)
            sf[nt][mq] = __builtin_amdgcn_mfma_f32_16x16x32_bf16(ak, bq[mq][ks], sf[nt][mq], 0, 0, 0);
        }
      }

      // P = exp2(S) (unnormalized; Q carries log2(e)/8), per-lane l accumulate
      #pragma unroll
      for (int nt = 0; nt < 4; nt++)
        #pragma unroll
        for (int mq = 0; mq < 2; mq++)
          #pragma unroll
          for (int r = 0; r < 4; r++)
            sf[nt][mq][r] = fexp2(sf[nt][mq][r]);
      #pragma unroll
      for (int mq = 0; mq < 2; mq++)
        #pragma unroll
        for (int nt = 0; nt < 4; nt++)
          li[mq] += (sf[nt][mq][0] + sf[nt][mq][1]) + (sf[nt][mq][2] + sf[nt][mq][3]);

      // O += P V: A-frags straight from regs (pack 2 stacked 16-kv tiles -> k=32)
      #pragma unroll
      for (int c = 0; c < 2; c++){
        bf16x8 ap[2];
        #pragma unroll
        for (int mq = 0; mq < 2; mq++){
          u32x4v aw;
          aw[0] = pk_bf16(sf[c * 2][mq][0],     sf[c * 2][mq][1]);
          aw[1] = pk_bf16(sf[c * 2][mq][2],     sf[c * 2][mq][3]);
          aw[2] = pk_bf16(sf[c * 2 + 1][mq][0], sf[c * 2 + 1][mq][1]);
          aw[3] = pk_bf16(sf[c * 2 + 1][mq][2], sf[c * 2 + 1][mq][3]);
          ap[mq] = __builtin_bit_cast(bf16x8, aw);
        }
        #pragma unroll
        for (int nt = 0; nt < 4; nt++){
          int rv = nt * 16 + l16;
          bf16x8 bv = as_bf(*(const u16x8*)&VTs[cur][(rv << 6) + ((((c << 2) + quad) ^ (rv & 7)) << 3)]);
          #pragma unroll
          for (int mq = 0; mq < 2; mq++)
            acc[mq][nt] = __builtin_amdgcn_mfma_f32_16x16x32_bf16(ap[mq], bv, acc[mq][nt], 0, 0, 0);
        }
      }

      // dump prefetched tile kt+1 into the other buffer, then ONE barrier
      if (kt < SEQ / 64 - 1){
        *(u16x8*)&Ks[cur ^ 1][dofs]  = kpre;
        *(u16x8*)&VTs[cur ^ 1][dofs] = vpre;
      }
      __syncthreads();
    }
  }

  // reduce l across the 4 quads (lanes l16, l16+16, l16+32, l16+48 share q)
  #pragma unroll
  for (int mq = 0; mq < 2; mq++){
    li[mq] += __shfl_xor(li[mq], 16);
    li[mq] += __shfl_xor(li[mq], 32);
  }
  float inv[2] = {1.0f / li[0], 1.0f / li[1]};
  float invr[2][4];
  #pragma unroll
  for (int mq = 0; mq < 2; mq++)
    #pragma unroll
    for (int r = 0; r < 4; r++)
      invr[mq][r] = __shfl(inv[mq], quad * 4 + r);

  // write O (bf16, [B,S,D]); O C-layout: col=d=l16, row=q=quad*4+r
  int b = bh >> 4, h = bh & 15;
  #pragma unroll
  for (int mq = 0; mq < 2; mq++)
    #pragma unroll
    for (int nt = 0; nt < 4; nt++)
      #pragma unroll
      for (int r = 0; r < 4; r++){
        int s = qt * 256 + w * 32 + mq * 16 + quad * 4 + r;
        int d = h * 64 + nt * 16 + l16;
        o_ws[((size_t)(b * SEQ + s)) * EMBED + d] = f2bf(acc[mq][nt][r] * invr[mq][r]);
      }
}

// ---------------- launch ----------------
// ws alias table (40 MB), R9-proven ordering:
//   [0,8M)   xb -> o     [8,16M) q     [16,24M) k
//   [24,32M) v (dead after vtrans) -> woutT [24,26M) via wtrans_out AFTER vtrans
//   [32,38M) wqkvT (dead after gemm_qkv) -> vt [32,40M)
extern "C" void kernel_launch(void* const* d_in, const int* in_sizes, int n_in,
                              void* d_out, int out_size, void* d_ws, size_t ws_size,
                              hipStream_t stream) {
  const float* x     = (const float*)d_in[0];
  const float* W_qkv = (const float*)d_in[1];
  const float* b_qkv = (const float*)d_in[2];
  const float* W_out = (const float*)d_in[3];
  const float* b_out = (const float*)d_in[4];
  float* out = (float*)d_out;

  char* ws = (char*)d_ws;
  unsigned short* xb    = (unsigned short*)(ws);
  unsigned short* q     = (unsigned short*)(ws + ((size_t)8  << 20));
  unsigned short* k     = (unsigned short*)(ws + ((size_t)16 << 20));
  unsigned short* v     = (unsigned short*)(ws + ((size_t)24 << 20));
  unsigned short* woutT = (unsigned short*)(ws + ((size_t)24 << 20));
  unsigned short* vt    = (unsigned short*)(ws + ((size_t)32 << 20));
  unsigned short* wqkvT = (unsigned short*)(ws + ((size_t)32 << 20));
  unsigned short* o     = xb;

  prep<<<dim3(7168), dim3(256), 0, stream>>>(x, xb, W_qkv, wqkvT);

  gemm_qkv<<<dim3(24, 32), dim3(256), 0, stream>>>(
      xb, wqkvT, b_qkv, q, k, v, 4096, 3072, 1024);

  vtrans<<<dim3(64, 2, 32), dim3(256), 0, stream>>>(v, vt);

  wtrans_out<<<dim3(32, 32), dim3(256), 0, stream>>>(W_out, woutT);

  attn<<<dim3(8, 32), dim3(512), 0, stream>>>(q, k, vt, o);

  gemm_out<<<dim3(16, 32), dim3(256), 0, stream>>>(
      o, woutT, b_out, out, 4096, 1024, 1024);
}